// Round 11
// baseline (682.645 us; speedup 1.0000x reference)
//
#include <hip/hip_runtime.h>
#include <hip/hip_bf16.h>

#define NODES 8192
#define INF_ 256
#define OUTF 128
#define LRALPHA 0.02f

typedef __bf16 bf16;
typedef bf16 bf16x8 __attribute__((ext_vector_type(8)));
typedef float f32x4 __attribute__((ext_vector_type(4)));
typedef float f32x16 __attribute__((ext_vector_type(16)));
typedef int i32x4 __attribute__((ext_vector_type(4)));

// ---------------- Kernel 0: bitpack adj (256MB int32 -> 8MB bitmask), single pass ----------
// Proven 43.6 us @ 5.87 TB/s. Bit c of u64 word (row*128 + c/64) = adj[row][c] != 0.
__global__ __launch_bounds__(256) void gat_pack_r11(
    const i32x4* __restrict__ adj4, unsigned char* __restrict__ mask8)
{
    const unsigned int tid = threadIdx.x;
    const size_t t = (size_t)blockIdx.x * 256 + tid;
    i32x4 v = adj4[t];
    unsigned int nib = (v[0] != 0 ? 1u : 0u) | (v[1] != 0 ? 2u : 0u)
                     | (v[2] != 0 ? 4u : 0u) | (v[3] != 0 ? 8u : 0u);
    unsigned int other = (unsigned int)__shfl_xor((int)nib, 1);
    if ((tid & 1) == 0) mask8[t >> 1] = (unsigned char)(nib | (other << 4));
}

// ---------------- Kernel 1: Wh = x@W1 + b1 -> WhbF (MFMA fragment order) + exp arrays ----
__global__ __launch_bounds__(256) void gat_prep_r11(
    const float* __restrict__ x, const float* __restrict__ W1,
    const float* __restrict__ b1, const float* __restrict__ a,
    const float* __restrict__ b_att,
    bf16* __restrict__ WhbF, float* __restrict__ E1,
    float* __restrict__ E2, float* __restrict__ F1, float* __restrict__ F2)
{
    __shared__ float xsT[64][36];    // [k][row], padded
    __shared__ float ws1[64][132];   // [k][col], padded
    __shared__ float wh[32][128];    // Wh tile f32

    const int t = threadIdx.x;
    const int rbase = blockIdx.x * 32;
    const int tr = t >> 5;   // 0..7  -> rows tr*4..+3
    const int tc = t & 31;   // 0..31 -> cols tc*4..+3

    f32x4 acc[4];
    f32x4 bias = *(const f32x4*)&b1[tc * 4];
#pragma unroll
    for (int i = 0; i < 4; ++i) acc[i] = bias;

    for (int kt = 0; kt < 4; ++kt) {
        const int kb = kt * 64;
        {   // stage x tile transposed: xsT[k][r] = x[rbase+r][kb+k]
            int r = t >> 3;            // 0..31
            int kq = (t & 7) * 8;      // 0..56
            f32x4 v0 = *(const f32x4*)&x[(size_t)(rbase + r) * INF_ + kb + kq];
            f32x4 v1 = *(const f32x4*)&x[(size_t)(rbase + r) * INF_ + kb + kq + 4];
#pragma unroll
            for (int i = 0; i < 4; ++i) xsT[kq + i][r] = v0[i];
#pragma unroll
            for (int i = 0; i < 4; ++i) xsT[kq + 4 + i][r] = v1[i];
        }
        {   // stage W1 tile: ws1[k][c] = W1[kb+k][c]
            int kr = t >> 2;           // 0..63
            int cq = (t & 3) * 32;
#pragma unroll
            for (int i = 0; i < 8; ++i) {
                f32x4 v = *(const f32x4*)&W1[(size_t)(kb + kr) * OUTF + cq + i * 4];
                *(f32x4*)&ws1[kr][cq + i * 4] = v;
            }
        }
        __syncthreads();
        for (int kk = 0; kk < 64; ++kk) {
            f32x4 xa = *(const f32x4*)&xsT[kk][tr * 4];
            f32x4 wb = *(const f32x4*)&ws1[kk][tc * 4];
#pragma unroll
            for (int i = 0; i < 4; ++i)
#pragma unroll
                for (int j = 0; j < 4; ++j)
                    acc[i][j] += xa[i] * wb[j];
        }
        __syncthreads();
    }

#pragma unroll
    for (int i = 0; i < 4; ++i)
        *(f32x4*)&wh[tr * 4 + i][tc * 4] = acc[i];
    __syncthreads();

    if (t < 32) {
        float s1 = 0.f, s2 = 0.f;
        for (int c = 0; c < OUTF; ++c) {
            float v = wh[t][c];
            s1 += v * a[c];
            s2 += v * a[OUTF + c];
        }
        float fsv = s1 + b_att[0];
        int r = rbase + t;
        E1[r] = expf(fsv);
        E2[r] = expf(LRALPHA * fsv);
        F1[r] = expf(s2);
        F2[r] = expf(LRALPHA * s2);
    }

    {   // WhbF fragment writes: thread t -> (kb, fb, c), two lane-halves h
        const int kb = t >> 7;          // 0..1
        const int fb = (t >> 5) & 3;    // 0..3
        const int c  = t & 31;          // feat within fb
        const size_t jblk = (size_t)blockIdx.x * 2 + kb;
#pragma unroll
        for (int h = 0; h < 2; ++h) {
            const int lane = c + h * 32;
            bf16x8 v;
#pragma unroll
            for (int e = 0; e < 8; ++e)
                v[e] = (bf16)wh[kb * 16 + h * 8 + e][fb * 32 + c];
            *(bf16x8*)&WhbF[((jblk * 4 + fb) * 64 + lane) * 8] = v;
        }
    }
}

// ---------------- Kernel 2: masked softmax weights + PV (bf16 MFMA), column-split ----------
// grid 512 = 256 row-groups x 2 column-halves; 1024 thr = 16 waves; wave owns 256 cols.
// launch_bounds(1024,8) caps VGPR at 64 -> 2 blocks/CU (LDS 69.6KB) -> 32 waves/CU.
// Writes raw partial P (f32) + partial den; combine kernel finishes. Cascade dumps acc
// in two half-phases so zones fit in 67.6KB (stride-33 slots, conflict-free).
#define DENRED_OFF 0
#define TAB_OFF    2048
#define ZONE_OFF   2048                 // zones alias tables (dead after main loop)
#define SLOT_BYTES 8448                 // 64 lanes * 33 f32 * 4B
#define SMEM2_SIZE (2048 + 8 * SLOT_BYTES)   // 69632 -> 2 blocks/CU

__global__ __launch_bounds__(1024, 8) void gat_attn_r11(
    const unsigned long long* __restrict__ m64,
    const bf16* __restrict__ WhbF,
    const float* __restrict__ E1, const float* __restrict__ E2,
    const float* __restrict__ F1, const float* __restrict__ F2,
    float* __restrict__ ppart, float* __restrict__ dpart)
{
    extern __shared__ char smem[];
    float* denred = (float*)(smem + DENRED_OFF);       // [16][32]
    float* F1t = (float*)(smem + TAB_OFF);             // 4096 f32 (this half)
    float* F2t = (float*)(smem + TAB_OFF + 16384);     // 4096 f32

    const int tid = threadIdx.x;
    const int lane = tid & 63;
    const int wv = tid >> 6;        // 0..15 : 256-col strip within half
    const int rg = blockIdx.x >> 1;
    const int half = blockIdx.x & 1;
    const int rbase = rg * 32;
    const int r = lane & 31;
    const int ag = lane >> 5;
    const int agsh = ag * 8;

    {   // stage this half's F1/F2 tables (4 floats per thread per table)
        int i = tid * 4;
        *(f32x4*)&F1t[i] = *(const f32x4*)&F1[half * 4096 + i];
        *(f32x4*)&F2t[i] = *(const f32x4*)&F2[half * 4096 + i];
    }

    const float e1v = E1[rbase + r];
    const float e2v = E2[rbase + r];
    const int j0 = wv * 256;                               // local col of strip
    const int sg0 = half * 256 + wv * 16;                  // global 16-col block idx
    const size_t mbase = (size_t)(rbase + r) * 128 + half * 64 + wv * 4;

    f32x16 acc0, acc1, acc2, acc3;
#pragma unroll
    for (int i = 0; i < 16; ++i) { acc0[i] = 0.f; acc1[i] = 0.f; acc2[i] = 0.f; acc3[i] = 0.f; }
    float den = 0.f;

    __syncthreads();   // tables staged

    unsigned long long myb = m64[mbase];
#pragma unroll
    for (int cb = 0; cb < 4; ++cb) {
        unsigned long long mybn = (cb < 3) ? m64[mbase + cb + 1] : 0ull;
#pragma unroll
        for (int i4 = 0; i4 < 4; ++i4) {
            const int s = cb * 4 + i4;
            const size_t fbase = (size_t)(sg0 + s) * 2048 + lane * 8;
            bf16x8 wc0 = *(const bf16x8*)&WhbF[fbase];
            bf16x8 wc1 = *(const bf16x8*)&WhbF[fbase + 512];
            bf16x8 wc2 = *(const bf16x8*)&WhbF[fbase + 1024];
            bf16x8 wc3 = *(const bf16x8*)&WhbF[fbase + 1536];

            const int jl = j0 + s * 16 + agsh;
            f32x4 g1a = *(const f32x4*)&F1t[jl];
            f32x4 g1b = *(const f32x4*)&F1t[jl + 4];
            f32x4 g2a = *(const f32x4*)&F2t[jl];
            f32x4 g2b = *(const f32x4*)&F2t[jl + 4];

            const unsigned int b8 = (unsigned int)(myb >> (i4 * 16 + agsh)) & 0xffu;

            bf16x8 wb;
#pragma unroll
            for (int jj = 0; jj < 4; ++jj) {
                float tv = e1v * g1a[jj];                 // e^s ; s>0 <=> tv>1
                float w = tv > 1.f ? tv : e2v * g2a[jj];
                w = (b8 & (1u << jj)) ? w : 0.f;
                den += w;
                wb[jj] = (bf16)w;
            }
#pragma unroll
            for (int jj = 0; jj < 4; ++jj) {
                float tv = e1v * g1b[jj];
                float w = tv > 1.f ? tv : e2v * g2b[jj];
                w = (b8 & (16u << jj)) ? w : 0.f;
                den += w;
                wb[4 + jj] = (bf16)w;
            }

            acc0 = __builtin_amdgcn_mfma_f32_32x32x16_bf16(wc0, wb, acc0, 0, 0, 0);
            acc1 = __builtin_amdgcn_mfma_f32_32x32x16_bf16(wc1, wb, acc1, 0, 0, 0);
            acc2 = __builtin_amdgcn_mfma_f32_32x32x16_bf16(wc2, wb, acc2, 0, 0, 0);
            acc3 = __builtin_amdgcn_mfma_f32_32x32x16_bf16(wc3, wb, acc3, 0, 0, 0);
        }
        myb = mybn;
    }

    den += __shfl_xor(den, 32);

    __syncthreads();   // main loop done everywhere; tables dead, zones live
    if (lane < 32) denred[wv * 32 + r] = den;

    // cascade 16 -> 1 in two half-acc phases per stage (zones: 8 x 8448B)
    auto dumpA = [&](int slot) {
        float* z = (float*)(smem + ZONE_OFF + (size_t)slot * SLOT_BYTES) + lane * 33;
        *(f32x16*)(z) = acc0; *(f32x16*)(z + 16) = acc1;
    };
    auto takeA = [&](int slot) {
        const float* z = (const float*)(smem + ZONE_OFF + (size_t)slot * SLOT_BYTES) + lane * 33;
        f32x16 v0 = *(const f32x16*)(z); f32x16 v1 = *(const f32x16*)(z + 16);
#pragma unroll
        for (int i = 0; i < 16; ++i) { acc0[i] += v0[i]; acc1[i] += v1[i]; }
    };
    auto dumpB = [&](int slot) {
        float* z = (float*)(smem + ZONE_OFF + (size_t)slot * SLOT_BYTES) + lane * 33;
        *(f32x16*)(z) = acc2; *(f32x16*)(z + 16) = acc3;
    };
    auto takeB = [&](int slot) {
        const float* z = (const float*)(smem + ZONE_OFF + (size_t)slot * SLOT_BYTES) + lane * 33;
        f32x16 v0 = *(const f32x16*)(z); f32x16 v1 = *(const f32x16*)(z + 16);
#pragma unroll
        for (int i = 0; i < 16; ++i) { acc2[i] += v0[i]; acc3[i] += v1[i]; }
    };

    // 16 -> 8
    if (wv >= 8) dumpA(wv - 8);
    __syncthreads();
    if (wv < 8) takeA(wv);
    __syncthreads();
    if (wv >= 8) dumpB(wv - 8);
    __syncthreads();
    if (wv < 8) takeB(wv);
    __syncthreads();
    // 8 -> 4
    if (wv >= 4 && wv < 8) dumpA(wv - 4);
    __syncthreads();
    if (wv < 4) takeA(wv);
    __syncthreads();
    if (wv >= 4 && wv < 8) dumpB(wv - 4);
    __syncthreads();
    if (wv < 4) takeB(wv);
    __syncthreads();
    // 4 -> 2
    if (wv == 2 || wv == 3) dumpA(wv - 2);
    __syncthreads();
    if (wv < 2) takeA(wv);
    __syncthreads();
    if (wv == 2 || wv == 3) dumpB(wv - 2);
    __syncthreads();
    if (wv < 2) takeB(wv);
    __syncthreads();
    // 2 -> 1
    if (wv == 1) dumpA(0);
    __syncthreads();
    if (wv == 0) takeA(0);
    __syncthreads();
    if (wv == 1) dumpB(0);
    __syncthreads();

    if (wv == 0) {
        takeB(0);
        float ds = 0.f;
#pragma unroll
        for (int w = 0; w < 16; ++w) ds += denred[w * 32 + r];
        if (lane < 32) dpart[half * NODES + rbase + r] = ds;

        float* pp = ppart + (size_t)half * NODES * OUTF + (size_t)(rbase + r) * OUTF;
#pragma unroll
        for (int fb = 0; fb < 4; ++fb) {
            const f32x16* A = (fb == 0) ? &acc0 : (fb == 1) ? &acc1 : (fb == 2) ? &acc2 : &acc3;
#pragma unroll
            for (int u = 0; u < 4; ++u) {
                f32x4 o;
#pragma unroll
                for (int e = 0; e < 4; ++e) o[e] = (*A)[4 * u + e];
                *(f32x4*)&pp[fb * 32 + 8 * u + 4 * ag] = o;
            }
        }
    }
}

// ---------------- Kernel 3: combine halves: out = elu((P0+P1)/(d0+d1)) ----------------
__global__ __launch_bounds__(1024) void gat_comb_r11(
    const float* __restrict__ ppart, const float* __restrict__ dpart,
    float* __restrict__ out)
{
    const size_t idx = ((size_t)blockIdx.x * 1024 + threadIdx.x) * 4;
    const int row = (int)(idx >> 7);
    f32x4 p0 = *(const f32x4*)&ppart[idx];
    f32x4 p1 = *(const f32x4*)&ppart[(size_t)NODES * OUTF + idx];
    const float inv = 1.f / (dpart[row] + dpart[NODES + row]);
    f32x4 o;
#pragma unroll
    for (int e = 0; e < 4; ++e) {
        float v = (p0[e] + p1[e]) * inv;
        o[e] = v > 0.f ? v : expm1f(v);
    }
    *(f32x4*)&out[idx] = o;
}

extern "C" void kernel_launch(void* const* d_in, const int* in_sizes, int n_in,
                              void* d_out, int out_size, void* d_ws, size_t ws_size,
                              hipStream_t stream) {
    const float* x     = (const float*)d_in[0];
    const int*   adj   = (const int*)d_in[1];
    const float* W1    = (const float*)d_in[2];
    const float* b1    = (const float*)d_in[3];
    const float* a     = (const float*)d_in[4];
    const float* b_att = (const float*)d_in[5];
    float* out = (float*)d_out;

    char* ws = (char*)d_ws;
    unsigned char* mask8 = (unsigned char*)ws;                 // 8 MB
    bf16* WhbF = (bf16*)(ws + (size_t)8 * 1024 * 1024);        // 2 MB
    float* E1 = (float*)(ws + (size_t)10 * 1024 * 1024);       // 4 x 32KB
    float* E2 = E1 + NODES;
    float* F1 = E2 + NODES;
    float* F2 = F1 + NODES;
    float* ppart = (float*)(ws + (size_t)12 * 1024 * 1024);    // 2 x 4 MB
    float* dpart = (float*)(ws + (size_t)20 * 1024 * 1024);    // 2 x 32 KB

    hipLaunchKernelGGL(gat_pack_r11, dim3(65536), dim3(256), 0, stream,
                       (const i32x4*)adj, mask8);

    hipLaunchKernelGGL(gat_prep_r11, dim3(NODES / 32), dim3(256), 0, stream,
                       x, W1, b1, a, b_att, WhbF, E1, E2, F1, F2);

    hipLaunchKernelGGL(gat_attn_r11, dim3(512), dim3(1024), SMEM2_SIZE, stream,
                       (const unsigned long long*)mask8, WhbF, E1, E2, F1, F2,
                       ppart, dpart);

    hipLaunchKernelGGL(gat_comb_r11, dim3(NODES * OUTF / 4096), dim3(1024), 0, stream,
                       ppart, dpart, out);
}